// Round 21
// baseline (3478.972 us; speedup 1.0000x reference)
//
#include <hip/hip_runtime.h>
#include <hip/hip_cooperative_groups.h>
#include <math.h>

namespace cg = cooperative_groups;

#define BB 64
#define SS 512
#define INF 64
#define HH 512
#define G5 2560

typedef unsigned short u16;
typedef __attribute__((ext_vector_type(8))) short short8v;
typedef __attribute__((ext_vector_type(4))) float f32x4;

// ---------------- init ----------------
__global__ void init_kernel(float* __restrict__ p, int n) {
    int i = blockIdx.x * blockDim.x + threadIdx.x;
    if (i < n) p[i] = 0.f;
}

// ---------------- bf16 two-term split ----------------
__device__ __forceinline__ void bf16_split(float f, u16& hi, u16& lo) {
    unsigned u = __float_as_uint(f);
    unsigned h = (u + 0x7FFFu + ((u >> 16) & 1u)) >> 16;
    float fh = __uint_as_float(h << 16);
    float r = f - fh;
    unsigned ur = __float_as_uint(r);
    unsigned l = (ur + 0x7FFFu + ((ur >> 16) & 1u)) >> 16;
    hi = (u16)h; lo = (u16)l;
}

__device__ __forceinline__ short8v ldfrag(const u16* p, int lane) {
    return *(const short8v*)(p + ((size_t)lane << 3));
}

// coherent A-frag load: coalesced dwordx4 bypassing L1+L2 (reads LLC).
// Result not ready until explicit s_waitcnt vmcnt(0) (caller does it).
__device__ __forceinline__ short8v llc_load(const u16* p, int lane) {
    short8v r;
    const u16* addr = p + ((size_t)lane << 3);
    asm volatile("global_load_dwordx4 %0, %1, off sc0 sc1"
                 : "=v"(r) : "v"(addr) : "memory");
    return r;
}

// ---------------- W -> bf16 hi/lo fragment tiles ----------------
// wf[(((J*5+g)*NS + s)*2 + term)*512 + l*8 + i]
__global__ __launch_bounds__(256) void wrepack_frag(
    const float* __restrict__ W, u16* __restrict__ wf, int NS)
{
    const int s = blockIdx.x, J = blockIdx.y;
    const int tid = threadIdx.x;
    for (int v = tid; v < 2560; v += 256) {
        int g = v >> 9, rem = v & 511, kloc = rem >> 4, jloc = rem & 15;
        float w = W[(size_t)(s * 32 + kloc) * G5 + g * 512 + J * 16 + jloc];
        u16 hi, lo; bf16_split(w, hi, lo);
        int l = ((kloc >> 3) << 4) | jloc;
        size_t base = ((((size_t)J * 5 + g) * NS + s) * 2) * 512;
        size_t off = (size_t)l * 8 + (kloc & 7);
        wf[base + off] = hi;
        wf[base + 512 + off] = lo;
    }
}

// ---------------- x -> A-frag tiles ----------------
// xf[((t*2+term)*2+s)*4*512 + m*512 + l*8 + i]
__global__ __launch_bounds__(256) void xfrag_kernel(
    const float* __restrict__ x, u16* __restrict__ xf)
{
    const int t = blockIdx.x, tid = threadIdx.x;
    const size_t tb = (size_t)t * 2 * 4096;
    for (int rep = 0; rep < 4; ++rep) {
        int rrow = (tid >> 4) + rep * 16;
        int kq = (tid & 15) * 4;
        float4 v = *(const float4*)(x + ((size_t)rrow * SS + t) * INF + kq);
        float vals[4] = {v.x, v.y, v.z, v.w};
        #pragma unroll
        for (int c = 0; c < 4; ++c) {
            int k = kq + c;
            int sloc = k >> 5, kloc = k & 31;
            int m = rrow >> 4, rowloc = rrow & 15;
            int l = rowloc | ((kloc >> 3) << 4);
            size_t off = (size_t)sloc * 2048 + m * 512 + l * 8 + (kloc & 7);
            u16 hi, lo; bf16_split(vals[c], hi, lo);
            xf[tb + off] = hi;
            xf[tb + 4096 + off] = lo;
        }
    }
}

// ---------------- decoupled per-(layer,m) sync primitives ----------------
// 8 domains (2 layers x 4 m-groups) of 32 blocks each. Cumulative counter at
// bar[dom*32], phase word at bar[dom*32+16] (separate lines).
__device__ __forceinline__ void dom_arrive(unsigned* bar, int dom, int step) {
    unsigned r = __hip_atomic_fetch_add(bar + dom * 32, 1u,
                                        __ATOMIC_RELAXED, __HIP_MEMORY_SCOPE_AGENT);
    if (r == (unsigned)(step + 1) * 32u - 1u)
        __hip_atomic_store(bar + dom * 32 + 16, (unsigned)(step + 1),
                           __ATOMIC_RELAXED, __HIP_MEMORY_SCOPE_AGENT);
}
// all-thread wait: wave-uniform poll, no leader/release rendezvous
__device__ __forceinline__ void dom_wait_all(unsigned* bar, int dom, int val) {
    while ((int)__hip_atomic_load(bar + dom * 32 + 16,
                                  __ATOMIC_RELAXED, __HIP_MEMORY_SCOPE_AGENT) < val) {}
}

// ---------------- fully-templated layer loop (resident W, split-issue) ------
// h0f: 4 parity slots (par = step&3). h1f: 2 parity slots.
// L0 work u: wait {phase0>=u, phase1>=u-3}; read x(u)+h0(u-1); write h0(u).
// L1 work w: wait {phase1>=w, phase0>=w+1}; read h0(w)+h1(w-1); write h1(w).
// Non-critical A-frags are issued BEFORE the self-domain wait (latency overlap).
template<bool ISL1>
__device__ __forceinline__ void run_layer(
    const u16* __restrict__ xf, const u16* __restrict__ wf,
    u16* __restrict__ h0f, u16* __restrict__ h1f,
    const float* __restrict__ bv, float* __restrict__ lstm_out,
    unsigned* __restrict__ bar, float (*red)[5][64][4])
{
    constexpr int NS   = ISL1 ? 32 : 18;
    constexpr int MAXK = ISL1 ? 4 : 3;     // ksteps per wave at stride 8

    const int tid  = threadIdx.x;
    const int lane = tid & 63;
    const int wv   = tid >> 6;             // 0..7
    const int blk  = (int)blockIdx.x & 127;
    const int qq = blk >> 3, rr = blk & 7;
    const int J = rr * 4 + (qq & 3);
    const int m = qq >> 2;
    const int domSelf  = (ISL1 ? 4 : 0) + m;
    const int domOther = (ISL1 ? 0 : 4) + m;

    const int rowloc = (tid & 255) >> 4, jloc = tid & 15;
    const int row = m * 16 + rowloc;
    const int jg  = J * 16 + jloc;
    const int ltid = ((rowloc >> 2) << 4) | jloc;
    const int itid = rowloc & 3;

    float bias[5];
    #pragma unroll
    for (int g = 0; g < 5; ++g) bias[g] = bv[g * HH + jg];

    const int wkloc = ((J & 1) << 4) | jloc;
    const int wof = ((J >> 1) * 4 + m) * 512
                  + (rowloc | ((wkloc >> 3) << 4)) * 8 + (jloc & 7);

    // ---- preload ALL W fragments for this wave (time-invariant) ----
    short8v wH[MAXK][5], wL[MAXK][5];
    #pragma unroll
    for (int i = 0; i < MAXK; ++i) {
        const int s = wv + 8 * i;
        if (s < NS) {
            #pragma unroll
            for (int g = 0; g < 5; ++g) {
                const u16* wb = wf + ((((size_t)J * 5 + g) * NS + s) * 2) * 512;
                wH[i][g] = ldfrag(wb, lane);
                wL[i][g] = ldfrag(wb + 512, lane);
            }
        }
    }

    float c_reg = 0.f;
    float pend  = 0.f;                     // deferred lstm_out value (L1 only)

    for (int w = 0; w < SS; ++w) {
        short8v aH[MAXK], aL[MAXK];

        // ---- phase A: non-critical waits + early A-frag issue ----
        if (ISL1) {
            dom_wait_all(bar, domOther, w + 1);               // h0(w) ready (L0 ahead)
            // h0(w) frags: i = 0,1 (s = wv, wv+8 < 16), parity w&3
            #pragma unroll
            for (int i = 0; i < 2; ++i) {
                const int s = wv + 8 * i;
                const u16* p0 = h0f + (size_t)((((w & 3) * 2 + 0) * 32768) + s * 2048 + m * 512);
                const u16* p1 = h0f + (size_t)((((w & 3) * 2 + 1) * 32768) + s * 2048 + m * 512);
                aH[i] = llc_load(p0, lane); aL[i] = llc_load(p1, lane);
            }
            // deferred lstm_out store (hidden in pre-wait window)
            if (w >= 1 && tid < 256)
                lstm_out[((size_t)row * SS + (w - 1)) * HH + jg] = pend;
        } else {
            if (w >= 4) dom_wait_all(bar, domOther, w - 3);   // h0 parity back-pressure
            // x(w) frags: s<2 (only waves with wv<2, i=0)
            if (wv < 2) {
                const u16* p0 = xf + (size_t)((w * 2 + 0) * 4096 + wv * 2048 + m * 512);
                const u16* p1 = xf + (size_t)((w * 2 + 1) * 4096 + wv * 2048 + m * 512);
                aH[0] = ldfrag(p0, lane); aL[0] = ldfrag(p1, lane);
            }
        }

        // ---- critical wait: self-domain (h-state recurrence) ----
        if (w >= 1) dom_wait_all(bar, domSelf, w);

        // ---- phase B: critical A-frag issue ----
        if (ISL1) {
            // h1(w-1) frags: i = 2,3 (s-16 = wv, wv+8), parity (w+1)&1
            #pragma unroll
            for (int i = 2; i < 4; ++i) {
                const int s = wv + 8 * i - 16;
                const u16* p0 = h1f + (size_t)(((((w + 1) & 1) * 2 + 0) * 32768) + s * 2048 + m * 512);
                const u16* p1 = h1f + (size_t)(((((w + 1) & 1) * 2 + 1) * 32768) + s * 2048 + m * 512);
                aH[i] = llc_load(p0, lane); aL[i] = llc_load(p1, lane);
            }
        } else {
            // h0(w-1) frags: all i with s>=2, parity (w+3)&3
            #pragma unroll
            for (int i = 0; i < MAXK; ++i) {
                const int s = wv + 8 * i;
                if (s >= 2 && s < NS) {
                    const u16* p0 = h0f + (size_t)(((((w + 3) & 3) * 2 + 0) * 32768) + (s - 2) * 2048 + m * 512);
                    const u16* p1 = h0f + (size_t)(((((w + 3) & 3) * 2 + 1) * 32768) + (s - 2) * 2048 + m * 512);
                    aH[i] = llc_load(p0, lane); aL[i] = llc_load(p1, lane);
                }
            }
        }

        // drain inline-asm loads before MFMA consumes them (rule #18)
        asm volatile("s_waitcnt vmcnt(0)" ::: "memory");
        __builtin_amdgcn_sched_barrier(0);

        f32x4 acc[5];
        #pragma unroll
        for (int g = 0; g < 5; ++g) acc[g] = (f32x4){0.f, 0.f, 0.f, 0.f};

        #pragma unroll
        for (int i = 0; i < MAXK; ++i) {
            const int s = wv + 8 * i;
            if (s < NS) {
                #pragma unroll
                for (int g = 0; g < 5; ++g) {
                    acc[g] = __builtin_amdgcn_mfma_f32_16x16x32_bf16(aH[i], wH[i][g], acc[g], 0, 0, 0);
                    acc[g] = __builtin_amdgcn_mfma_f32_16x16x32_bf16(aH[i], wL[i][g], acc[g], 0, 0, 0);
                    acc[g] = __builtin_amdgcn_mfma_f32_16x16x32_bf16(aL[i], wH[i][g], acc[g], 0, 0, 0);
                }
            }
        }

        #pragma unroll
        for (int g = 0; g < 5; ++g)
            *(f32x4*)&red[wv][g][lane][0] = acc[g];
        __syncthreads();

        if (tid < 256) {
            float gv[5];
            #pragma unroll
            for (int g = 0; g < 5; ++g)
                gv[g] = ((red[0][g][ltid][itid] + red[1][g][ltid][itid])
                      +  (red[2][g][ltid][itid] + red[3][g][ltid][itid]))
                      + ((red[4][g][ltid][itid] + red[5][g][ltid][itid])
                      +  (red[6][g][ltid][itid] + red[7][g][ltid][itid]))
                      + bias[g];

            float f  = 1.f / (1.f + expf(-gv[0]));
            float i_ = 1.f / (1.f + expf(-gv[1]));
            float ch = tanhf(gv[2]);
            float o  = 1.f / (1.f + expf(-gv[3]));
            float e_ = 1.f / (1.f + expf(-gv[4]));

            c_reg = f * c_reg + i_ * ch;
            float hl = o * tanhf(c_reg);
            float hn = e_ * expf(hl) + (1.f - e_) * hl;

            u16 hi, lo; bf16_split(hn, hi, lo);
            if (ISL1) {
                const int par = w & 1;
                __hip_atomic_store(h1f + (size_t)((par * 2 + 0) * 32768) + wof, hi,
                                   __ATOMIC_RELAXED, __HIP_MEMORY_SCOPE_AGENT);
                __hip_atomic_store(h1f + (size_t)((par * 2 + 1) * 32768) + wof, lo,
                                   __ATOMIC_RELAXED, __HIP_MEMORY_SCOPE_AGENT);
                pend = hn;
            } else {
                const int par = w & 3;
                __hip_atomic_store(h0f + (size_t)((par * 2 + 0) * 32768) + wof, hi,
                                   __ATOMIC_RELAXED, __HIP_MEMORY_SCOPE_AGENT);
                __hip_atomic_store(h0f + (size_t)((par * 2 + 1) * 32768) + wof, lo,
                                   __ATOMIC_RELAXED, __HIP_MEMORY_SCOPE_AGENT);
            }
        }
        __syncthreads();                  // drain h stores (vmcnt) before arrival
        if (tid == 0) dom_arrive(bar, domSelf, w);
    }
    // flush final deferred lstm_out value (work item SS-1)
    if (ISL1 && threadIdx.x < 256)
        lstm_out[((size_t)row * SS + (SS - 1)) * HH + jg] = pend;
}

// ---------------- persistent MFMA kernel ----------------
// 256 blocks x 512 threads = {L0: 0..127, L1: 128..255} x {J 0..31} x {m 0..3}
__global__ __launch_bounds__(512, 1) void persist_mfma(
    const u16* __restrict__ xf,
    const u16* __restrict__ wf0, const u16* __restrict__ wf1,
    const float* __restrict__ b0v, const float* __restrict__ b1v,
    u16* __restrict__ h0f, u16* __restrict__ h1f,
    float* __restrict__ lstm_out, unsigned* __restrict__ bar)
{
    __shared__ float red[8][5][64][4];          // 40 KB
    if (blockIdx.x >= 128)
        run_layer<true >(xf, wf1, h0f, h1f, b1v, lstm_out, bar, red);
    else
        run_layer<false>(xf, wf0, h0f, h1f, b0v, lstm_out, bar, red);
}

// ================= fallback path (R9, proven) =================
__global__ __launch_bounds__(256) void repack_kernel(
    const float* __restrict__ W, float* __restrict__ P, int K)
{
    __shared__ float tile[64][65];
    const int tid = threadIdx.x;
    const int kt = blockIdx.x;
    const int c0 = blockIdx.y * 64;

    for (int e = tid; e < 64 * 16; e += 256) {
        int kr = e >> 4, cq = (e & 15) * 4;
        float4 v = *(const float4*)(W + (size_t)(kt * 64 + kr) * G5 + c0 + cq);
        tile[kr][cq + 0] = v.x; tile[kr][cq + 1] = v.y;
        tile[kr][cq + 2] = v.z; tile[kr][cq + 3] = v.w;
    }
    __syncthreads();

    const int gate = c0 >> 9;
    const int jb   = c0 & 511;
    for (int e = tid; e < 64 * 16; e += 256) {
        int lr = e >> 4;
        int kq = (e & 15) * 4;
        int j  = jb + lr;
        int g  = j >> 1;
        int c  = j & 1;
        int orow = g * 10 + gate * 2 + c;
        float4 v;
        v.x = tile[kq + 0][lr]; v.y = tile[kq + 1][lr];
        v.z = tile[kq + 2][lr]; v.w = tile[kq + 3][lr];
        *(float4*)(P + (size_t)orow * K + kt * 64 + kq) = v;
    }
}

__global__ __launch_bounds__(256) void xpose_kernel(
    const float* __restrict__ x, float* __restrict__ xT)
{
    __shared__ float tile[64][68];
    const int tid = threadIdx.x;
    const int t = blockIdx.x;

    for (int e = tid; e < 64 * 16; e += 256) {
        int row = e >> 4, kq = (e & 15) * 4;
        float4 v = *(const float4*)(x + ((size_t)row * SS + t) * INF + kq);
        tile[row][kq + 0] = v.x; tile[row][kq + 1] = v.y;
        tile[row][kq + 2] = v.z; tile[row][kq + 3] = v.w;
    }
    __syncthreads();
    float* dst = xT + (size_t)t * (INF * BB);
    for (int e = tid; e < INF * BB; e += 256) {
        int k = e >> 6, r = e & 63;
        dst[(k >> 2) * 256 + r * 4 + (k & 3)] = tile[r][k];
    }
}

__device__ __forceinline__ void gemm_seg(
    const float4* __restrict__ ap, const float4* __restrict__ wq,
    int K4, int nq, float* __restrict__ acc)
{
    #pragma unroll 2
    for (int q = 0; q < nq; ++q) {
        float4 a  = ap[q * 64];
        float4 w0 = wq[q + 0 * K4];
        float4 w1 = wq[q + 1 * K4];
        float4 w2 = wq[q + 2 * K4];
        float4 w3 = wq[q + 3 * K4];
        float4 w4 = wq[q + 4 * K4];
        float4 w5 = wq[q + 5 * K4];
        float4 w6 = wq[q + 6 * K4];
        float4 w7 = wq[q + 7 * K4];
        float4 w8 = wq[q + 8 * K4];
        float4 w9 = wq[q + 9 * K4];
        acc[0]=fmaf(a.x,w0.x,acc[0]); acc[0]=fmaf(a.y,w0.y,acc[0]);
        acc[0]=fmaf(a.z,w0.z,acc[0]); acc[0]=fmaf(a.w,w0.w,acc[0]);
        acc[1]=fmaf(a.x,w1.x,acc[1]); acc[1]=fmaf(a.y,w1.y,acc[1]);
        acc[1]=fmaf(a.z,w1.z,acc[1]); acc[1]=fmaf(a.w,w1.w,acc[1]);
        acc[2]=fmaf(a.x,w2.x,acc[2]); acc[2]=fmaf(a.y,w2.y,acc[2]);
        acc[2]=fmaf(a.z,w2.z,acc[2]); acc[2]=fmaf(a.w,w2.w,acc[2]);
        acc[3]=fmaf(a.x,w3.x,acc[3]); acc[3]=fmaf(a.y,w3.y,acc[3]);
        acc[3]=fmaf(a.z,w3.z,acc[3]); acc[3]=fmaf(a.w,w3.w,acc[3]);
        acc[4]=fmaf(a.x,w4.x,acc[4]); acc[4]=fmaf(a.y,w4.y,acc[4]);
        acc[4]=fmaf(a.z,w4.z,acc[4]); acc[4]=fmaf(a.w,w4.w,acc[4]);
        acc[5]=fmaf(a.x,w5.x,acc[5]); acc[5]=fmaf(a.y,w5.y,acc[5]);
        acc[5]=fmaf(a.z,w5.z,acc[5]); acc[5]=fmaf(a.w,w5.w,acc[5]);
        acc[6]=fmaf(a.x,w6.x,acc[6]); acc[6]=fmaf(a.y,w6.y,acc[6]);
        acc[6]=fmaf(a.z,w6.z,acc[6]); acc[6]=fmaf(a.w,w6.w,acc[6]);
        acc[7]=fmaf(a.x,w7.x,acc[7]); acc[7]=fmaf(a.y,w7.y,acc[7]);
        acc[7]=fmaf(a.z,w7.z,acc[7]); acc[7]=fmaf(a.w,w7.w,acc[7]);
        acc[8]=fmaf(a.x,w8.x,acc[8]); acc[8]=fmaf(a.y,w8.y,acc[8]);
        acc[8]=fmaf(a.z,w8.z,acc[8]); acc[8]=fmaf(a.w,w8.w,acc[8]);
        acc[9]=fmaf(a.x,w9.x,acc[9]); acc[9]=fmaf(a.y,w9.y,acc[9]);
        acc[9]=fmaf(a.z,w9.z,acc[9]); acc[9]=fmaf(a.w,w9.w,acc[9]);
    }
}

__global__ __launch_bounds__(256, 2) void step512_kernel(
    const float* __restrict__ xT,
    const float* __restrict__ P0, const float* __restrict__ b0v,
    const float* __restrict__ P1, const float* __restrict__ b1v,
    float* __restrict__ h0buf, float* __restrict__ h1buf,
    float* __restrict__ c0buf, float* __restrict__ c1buf,
    float* __restrict__ lstm_out, int t)
{
    __shared__ float W_s[10 * 1024];
    __shared__ float red[4][10][64];

    const int tid  = threadIdx.x;
    const int lane = tid & 63;
    const int wv   = tid >> 6;
    const bool isL1 = (blockIdx.x >= 256);
    const int blk  = (int)blockIdx.x & 255;
    const int g    = (blk & 7) * 32 + (blk >> 3);
    const int j    = g * 2 + (wv & 1);

    const bool active = isL1 ? (t >= 1) : (t < SS);
    if (!active) return;

    const int K  = isL1 ? 1024 : 576;
    const int K4 = K >> 2;
    const int QK = K >> 2;
    const int k0 = wv * QK;

    {
        const float* Pg = (isL1 ? P1 : P0) + (size_t)g * 10 * K;
        const int n4 = 10 * K / 4;
        for (int i = tid; i < n4; i += 256)
            *(float4*)&W_s[i * 4] = *(const float4*)(Pg + (size_t)i * 4);
    }
    __syncthreads();

    const int tm1 = t - 1;
    const float* h0prev = h0buf + ((t + 1) & 1) * (BB * HH);
    const float* h0cur  = h0buf + (tm1 & 1) * (BB * HH);
    const float* h1prev = h1buf + ((tm1 + 1) & 1) * (BB * HH);

    const float4* wq0 = (const float4*)W_s + (k0 >> 2);

    float acc[10];
    #pragma unroll
    for (int r = 0; r < 10; ++r) acc[r] = 0.f;

    if (!isL1) {
        if (wv == 0) {
            const float4* aX = (const float4*)(xT + (size_t)t * (INF * BB)) + lane;
            const float4* aH = (const float4*)h0prev + lane;
            gemm_seg(aX, wq0,      K4, 16, acc);
            gemm_seg(aH, wq0 + 16, K4, 20, acc);
        } else {
            const float4* aH = (const float4*)h0prev + (36 * wv - 16) * 64 + lane;
            gemm_seg(aH, wq0, K4, 36, acc);
        }
    } else {
        const float* src = (wv < 2) ? h0cur : h1prev;
        const float4* aH = (const float4*)src + (wv & 2 ? (wv - 2) : wv) * 4096 + lane;
        gemm_seg(aH, wq0, K4, 64, acc);
    }

    #pragma unroll
    for (int r = 0; r < 10; ++r) red[wv][r][lane] = acc[r];
    __syncthreads();

    if (wv < 2) {
        const float* bv = isL1 ? b1v : b0v;
        float gv[5];
        #pragma unroll
        for (int gate = 0; gate < 5; ++gate) {
            int r = gate * 2 + wv;
            gv[gate] = red[0][r][lane] + red[1][r][lane]
                     + red[2][r][lane] + red[3][r][lane] + bv[gate * HH + j];
        }
        float f  = 1.f / (1.f + expf(-gv[0]));
        float i_ = 1.f / (1.f + expf(-gv[1]));
        float ch = tanhf(gv[2]);
        float o  = 1.f / (1.f + expf(-gv[3]));
        float e_ = 1.f / (1.f + expf(-gv[4]));

        float* cb = (isL1 ? c1buf : c0buf) + j * BB + lane;
        float c = f * (*cb) + i_ * ch;
        *cb = c;
        float hl = o * tanhf(c);
        float hn = e_ * expf(hl) + (1.f - e_) * hl;

        const int hoff = (j >> 2) * 256 + lane * 4 + (j & 3);
        if (!isL1) {
            h0buf[(t & 1) * (BB * HH) + hoff] = hn;
        } else {
            h1buf[(tm1 & 1) * (BB * HH) + hoff] = hn;
            lstm_out[((size_t)lane * SS + tm1) * HH + j] = hn;
        }
    }
}

// ---------------- attention epilogue ----------------
__global__ __launch_bounds__(256) void attn_kernel(
    const float* __restrict__ lstm_out,
    const float* __restrict__ Wa, const float* __restrict__ ba,
    const float* __restrict__ Wfc, const float* __restrict__ bfc,
    float* __restrict__ dout)
{
    const int b = blockIdx.x;
    const int tid = threadIdx.x;
    const int lane = tid & 63;
    const int wave = tid >> 6;

    __shared__ float wa_s[HH];
    __shared__ float logit[SS];
    __shared__ float wred[4];

    for (int ii = tid; ii < HH; ii += 256) wa_s[ii] = Wa[ii];
    __syncthreads();

    const float* Lb = lstm_out + (size_t)b * SS * HH;

    for (int tt = wave; tt < SS; tt += 4) {
        const float* rowp = Lb + (size_t)tt * HH;
        float s = 0.f;
        for (int jc = lane; jc < HH; jc += 64) s += rowp[jc] * wa_s[jc];
        #pragma unroll
        for (int off = 32; off > 0; off >>= 1) s += __shfl_down(s, off, 64);
        if (lane == 0) logit[tt] = s + ba[0];
    }
    __syncthreads();

    float m = -1e30f;
    for (int ii = tid; ii < SS; ii += 256) m = fmaxf(m, logit[ii]);
    #pragma unroll
    for (int off = 32; off > 0; off >>= 1) m = fmaxf(m, __shfl_down(m, off, 64));
    if (lane == 0) wred[wave] = m;
    __syncthreads();
    m = fmaxf(fmaxf(wred[0], wred[1]), fmaxf(wred[2], wred[3]));
    __syncthreads();

    float ssum = 0.f;
    for (int ii = tid; ii < SS; ii += 256) {
        float e = expf(logit[ii] - m);
        logit[ii] = e;
        ssum += e;
    }
    #pragma unroll
    for (int off = 32; off > 0; off >>= 1) ssum += __shfl_down(ssum, off, 64);
    if (lane == 0) wred[wave] = ssum;
    __syncthreads();
    ssum = wred[0] + wred[1] + wred[2] + wred[3];
    float inv = 1.f / ssum;
    __syncthreads();

    for (int ii = tid; ii < SS; ii += 256) {
        float a = logit[ii] * inv;
        logit[ii] = a;
        dout[BB + (size_t)b * SS + ii] = a;
    }
    __syncthreads();

    float ctx0 = 0.f, ctx1 = 0.f;
    for (int tt = 0; tt < SS; ++tt) {
        float a = logit[tt];
        ctx0 += a * Lb[(size_t)tt * HH + tid];
        ctx1 += a * Lb[(size_t)tt * HH + tid + 256];
    }

    float p = ctx0 * Wfc[tid] + ctx1 * Wfc[tid + 256];
    #pragma unroll
    for (int off = 32; off > 0; off >>= 1) p += __shfl_down(p, off, 64);
    __syncthreads();
    if (lane == 0) wred[wave] = p;
    __syncthreads();
    if (tid == 0) dout[b] = wred[0] + wred[1] + wred[2] + wred[3] + bfc[0];
}

extern "C" void kernel_launch(void* const* d_in, const int* in_sizes, int n_in,
                              void* d_out, int out_size, void* d_ws, size_t ws_size,
                              hipStream_t stream) {
    const float* x   = (const float*)d_in[0];
    const float* W0  = (const float*)d_in[1];
    const float* b0  = (const float*)d_in[2];
    const float* W1  = (const float*)d_in[3];
    const float* b1  = (const float*)d_in[4];
    const float* Wa  = (const float*)d_in[5];
    const float* ba  = (const float*)d_in[6];
    const float* Wfc = (const float*)d_in[7];
    const float* bfc = (const float*)d_in[8];
    float* out = (float*)d_out;
    float* ws  = (float*)d_ws;

    float* h0q  = ws;                              // 2*B*H (fallback)
    float* h1q  = h0q + 2 * BB * HH;               // 2*B*H (fallback)
    float* c0   = h1q + 2 * BB * HH;               // B*H (fallback)
    float* c1   = c0 + BB * HH;                    // B*H (fallback)
    u16*   h0f  = (u16*)(c1 + BB * HH);            // 262144 u16 (4 par x 2 term)
    u16*   h1f  = h0f + 262144;                    // 131072 u16 (2 par x 2 term)
    unsigned* bar = (unsigned*)(h1f + 131072);     // 1024 u32 (8 doms x 32)
    float* lstm = (float*)(bar + 1024);            // B*S*H
    float* WA   = lstm + (size_t)BB * SS * HH;     // P0 (fb) == wf0 (frag)
    float* WB   = WA + (size_t)G5 * (INF + HH);    // P1 (fb) == wf1 (frag)
    float* XF   = WB + (size_t)G5 * (HH + HH);     // xT (fb) == xf (frag)
    u16* wf0 = (u16*)WA;
    u16* wf1 = (u16*)WB;
    u16* xf  = (u16*)XF;

    // zero: fallback state (196608 f) + h0f (131072 f) + h1f (65536 f) + bar (1024 f)
    const int n_init = 6 * BB * HH + 262144 / 2 + 131072 / 2 + 1024;
    init_kernel<<<(n_init + 255) / 256, 256, 0, stream>>>(ws, n_init);

    wrepack_frag<<<dim3(18, 32), 256, 0, stream>>>(W0, wf0, 18);
    wrepack_frag<<<dim3(32, 32), 256, 0, stream>>>(W1, wf1, 32);
    xfrag_kernel<<<SS, 256, 0, stream>>>(x, xf);

    void* args[] = { (void*)&xf, (void*)&wf0, (void*)&wf1, (void*)&b0, (void*)&b1,
                     (void*)&h0f, (void*)&h1f, (void*)&lstm, (void*)&bar };
    hipError_t cerr = hipLaunchCooperativeKernel((void*)persist_mfma,
                                                 dim3(256), dim3(512),
                                                 args, 0, stream);
    if (cerr != hipSuccess) {
        repack_kernel<<<dim3((INF + HH) / 64, 40), 256, 0, stream>>>(W0, WA, INF + HH);
        repack_kernel<<<dim3((HH + HH) / 64, 40), 256, 0, stream>>>(W1, WB, HH + HH);
        xpose_kernel<<<SS, 256, 0, stream>>>(x, XF);
        for (int t = 0; t <= SS; ++t) {
            step512_kernel<<<512, 256, 0, stream>>>(XF, WA, b0, WB, b1,
                                                    h0q, h1q, c0, c1, lstm, t);
        }
    }

    attn_kernel<<<BB, 256, 0, stream>>>(lstm, Wa, ba, Wfc, bfc, out);
}

// Round 22
// 2118.108 us; speedup vs baseline: 1.6425x; 1.6425x over previous
//
#include <hip/hip_runtime.h>
#include <hip/hip_cooperative_groups.h>
#include <math.h>

namespace cg = cooperative_groups;

#define BB 64
#define SS 512
#define INF 64
#define HH 512
#define G5 2560

typedef unsigned short u16;
typedef __attribute__((ext_vector_type(8))) short short8v;
typedef __attribute__((ext_vector_type(4))) float f32x4;

// ---------------- init ----------------
__global__ void init_kernel(float* __restrict__ p, int n) {
    int i = blockIdx.x * blockDim.x + threadIdx.x;
    if (i < n) p[i] = 0.f;
}

// ---------------- bf16 two-term split ----------------
__device__ __forceinline__ void bf16_split(float f, u16& hi, u16& lo) {
    unsigned u = __float_as_uint(f);
    unsigned h = (u + 0x7FFFu + ((u >> 16) & 1u)) >> 16;
    float fh = __uint_as_float(h << 16);
    float r = f - fh;
    unsigned ur = __float_as_uint(r);
    unsigned l = (ur + 0x7FFFu + ((ur >> 16) & 1u)) >> 16;
    hi = (u16)h; lo = (u16)l;
}

__device__ __forceinline__ short8v ldfrag(const u16* p, int lane) {
    return *(const short8v*)(p + ((size_t)lane << 3));
}

// coherent A-frag load: coalesced dwordx4 bypassing L1+L2 (reads LLC).
// Result not ready until explicit s_waitcnt vmcnt(0) (caller does it).
__device__ __forceinline__ short8v llc_load(const u16* p, int lane) {
    short8v r;
    const u16* addr = p + ((size_t)lane << 3);
    asm volatile("global_load_dwordx4 %0, %1, off sc0 sc1"
                 : "=v"(r) : "v"(addr) : "memory");
    return r;
}

// ---------------- W -> bf16 hi/lo fragment tiles ----------------
// wf[(((J*5+g)*NS + s)*2 + term)*512 + l*8 + i]
__global__ __launch_bounds__(256) void wrepack_frag(
    const float* __restrict__ W, u16* __restrict__ wf, int NS)
{
    const int s = blockIdx.x, J = blockIdx.y;
    const int tid = threadIdx.x;
    for (int v = tid; v < 2560; v += 256) {
        int g = v >> 9, rem = v & 511, kloc = rem >> 4, jloc = rem & 15;
        float w = W[(size_t)(s * 32 + kloc) * G5 + g * 512 + J * 16 + jloc];
        u16 hi, lo; bf16_split(w, hi, lo);
        int l = ((kloc >> 3) << 4) | jloc;
        size_t base = ((((size_t)J * 5 + g) * NS + s) * 2) * 512;
        size_t off = (size_t)l * 8 + (kloc & 7);
        wf[base + off] = hi;
        wf[base + 512 + off] = lo;
    }
}

// ---------------- x -> A-frag tiles ----------------
// xf[((t*2+term)*2+s)*4*512 + m*512 + l*8 + i]
__global__ __launch_bounds__(256) void xfrag_kernel(
    const float* __restrict__ x, u16* __restrict__ xf)
{
    const int t = blockIdx.x, tid = threadIdx.x;
    const size_t tb = (size_t)t * 2 * 4096;
    for (int rep = 0; rep < 4; ++rep) {
        int rrow = (tid >> 4) + rep * 16;
        int kq = (tid & 15) * 4;
        float4 v = *(const float4*)(x + ((size_t)rrow * SS + t) * INF + kq);
        float vals[4] = {v.x, v.y, v.z, v.w};
        #pragma unroll
        for (int c = 0; c < 4; ++c) {
            int k = kq + c;
            int sloc = k >> 5, kloc = k & 31;
            int m = rrow >> 4, rowloc = rrow & 15;
            int l = rowloc | ((kloc >> 3) << 4);
            size_t off = (size_t)sloc * 2048 + m * 512 + l * 8 + (kloc & 7);
            u16 hi, lo; bf16_split(vals[c], hi, lo);
            xf[tb + off] = hi;
            xf[tb + 4096 + off] = lo;
        }
    }
}

// ---------------- decoupled per-(layer,m) sync primitives ----------------
// 8 domains (2 layers x 4 m-groups) of 32 blocks each. Cumulative counter at
// bar[dom*32], phase word at bar[dom*32+16] (separate lines). Arrival: add;
// the 32nd arriver stores phase = step+1. Waiters poll phase words only.
__device__ __forceinline__ void dom_arrive(unsigned* bar, int dom, int step) {
    unsigned r = __hip_atomic_fetch_add(bar + dom * 32, 1u,
                                        __ATOMIC_RELAXED, __HIP_MEMORY_SCOPE_AGENT);
    if (r == (unsigned)(step + 1) * 32u - 1u)
        __hip_atomic_store(bar + dom * 32 + 16, (unsigned)(step + 1),
                           __ATOMIC_RELAXED, __HIP_MEMORY_SCOPE_AGENT);
}
__device__ __forceinline__ void dom_wait(unsigned* bar, int dom, int val) {
    while ((int)__hip_atomic_load(bar + dom * 32 + 16,
                                  __ATOMIC_RELAXED, __HIP_MEMORY_SCOPE_AGENT) < val) {}
}

// ---------------- fully-templated layer loop (resident W, decoupled sync) ---
// h0f: 4 parity slots (par = step&3). h1f: 2 parity slots.
// L0 work u: wait {phase0>=u, phase1>=u-3}; read x(u)+h0(u-1); write h0(u).
// L1 work w: wait {phase1>=w, phase0>=w+1}; read h0(w)+h1(w-1); write h1(w).
template<bool ISL1>
__device__ __forceinline__ void run_layer(
    const u16* __restrict__ xf, const u16* __restrict__ wf,
    u16* __restrict__ h0f, u16* __restrict__ h1f,
    const float* __restrict__ bv, float* __restrict__ lstm_out,
    unsigned* __restrict__ bar, float (*red)[5][64][4])
{
    constexpr int NS   = ISL1 ? 32 : 18;
    constexpr int MAXK = ISL1 ? 4 : 3;     // ksteps per wave at stride 8

    const int tid  = threadIdx.x;
    const int lane = tid & 63;
    const int wv   = tid >> 6;             // 0..7
    const int blk  = (int)blockIdx.x & 127;
    const int qq = blk >> 3, rr = blk & 7;
    const int J = rr * 4 + (qq & 3);
    const int m = qq >> 2;
    const int domSelf  = (ISL1 ? 4 : 0) + m;
    const int domOther = (ISL1 ? 0 : 4) + m;

    const int rowloc = (tid & 255) >> 4, jloc = tid & 15;
    const int row = m * 16 + rowloc;
    const int jg  = J * 16 + jloc;
    const int ltid = ((rowloc >> 2) << 4) | jloc;
    const int itid = rowloc & 3;

    float bias[5];
    #pragma unroll
    for (int g = 0; g < 5; ++g) bias[g] = bv[g * HH + jg];

    const int wkloc = ((J & 1) << 4) | jloc;
    const int wof = ((J >> 1) * 4 + m) * 512
                  + (rowloc | ((wkloc >> 3) << 4)) * 8 + (jloc & 7);

    // ---- preload ALL W fragments for this wave (time-invariant) ----
    short8v wH[MAXK][5], wL[MAXK][5];
    #pragma unroll
    for (int i = 0; i < MAXK; ++i) {
        const int s = wv + 8 * i;
        if (s < NS) {
            #pragma unroll
            for (int g = 0; g < 5; ++g) {
                const u16* wb = wf + ((((size_t)J * 5 + g) * NS + s) * 2) * 512;
                wH[i][g] = ldfrag(wb, lane);
                wL[i][g] = ldfrag(wb + 512, lane);
            }
        }
    }

    float c_reg = 0.f;
    float pend  = 0.f;                     // deferred lstm_out value (L1 only)

    for (int w = 0; w < SS; ++w) {
        // ---- waits (leader only; block released by the syncthreads below) ----
        if (tid == 0) {
            if (ISL1) {
                if (w >= 1) dom_wait(bar, domSelf, w);        // h1(w-1) ready
                dom_wait(bar, domOther, w + 1);               // h0(w) ready
            } else {
                if (w >= 1) dom_wait(bar, domSelf, w);        // h0(w-1) ready
                if (w >= 4) dom_wait(bar, domOther, w - 3);   // h0 parity back-pressure
            }
        }
        __syncthreads();

        // deferred lstm_out store from previous work item (hidden under compute)
        if (ISL1 && w >= 1 && tid < 256)
            lstm_out[((size_t)row * SS + (w - 1)) * HH + jg] = pend;

        // ---- issue ALL A-frag loads (coalesced, batched) ----
        short8v aH[MAXK], aL[MAXK];
        #pragma unroll
        for (int i = 0; i < MAXK; ++i) {
            const int s = wv + 8 * i;
            if (s < NS) {
                if (ISL1) {
                    const u16* p0;
                    const u16* p1;
                    if (s < 16) {          // h0(w), parity w&3
                        p0 = h0f + (size_t)((((w & 3) * 2 + 0) * 32768) + s * 2048 + m * 512);
                        p1 = h0f + (size_t)((((w & 3) * 2 + 1) * 32768) + s * 2048 + m * 512);
                    } else {               // h1(w-1), parity (w+1)&1
                        p0 = h1f + (size_t)(((((w + 1) & 1) * 2 + 0) * 32768) + (s - 16) * 2048 + m * 512);
                        p1 = h1f + (size_t)(((((w + 1) & 1) * 2 + 1) * 32768) + (s - 16) * 2048 + m * 512);
                    }
                    aH[i] = llc_load(p0, lane); aL[i] = llc_load(p1, lane);
                } else {
                    if (s < 2) {           // x(w)
                        const u16* p0 = xf + (size_t)((w * 2 + 0) * 4096 + s * 2048 + m * 512);
                        const u16* p1 = xf + (size_t)((w * 2 + 1) * 4096 + s * 2048 + m * 512);
                        aH[i] = ldfrag(p0, lane); aL[i] = ldfrag(p1, lane);
                    } else {               // h0(w-1), parity (w+3)&3
                        const u16* p0 = h0f + (size_t)(((((w + 3) & 3) * 2 + 0) * 32768) + (s - 2) * 2048 + m * 512);
                        const u16* p1 = h0f + (size_t)(((((w + 3) & 3) * 2 + 1) * 32768) + (s - 2) * 2048 + m * 512);
                        aH[i] = llc_load(p0, lane); aL[i] = llc_load(p1, lane);
                    }
                }
            }
        }

        // drain inline-asm loads before MFMA consumes them (rule #18)
        asm volatile("s_waitcnt vmcnt(0)" ::: "memory");
        __builtin_amdgcn_sched_barrier(0);

        f32x4 acc[5];
        #pragma unroll
        for (int g = 0; g < 5; ++g) acc[g] = (f32x4){0.f, 0.f, 0.f, 0.f};

        #pragma unroll
        for (int i = 0; i < MAXK; ++i) {
            const int s = wv + 8 * i;
            if (s < NS) {
                #pragma unroll
                for (int g = 0; g < 5; ++g) {
                    acc[g] = __builtin_amdgcn_mfma_f32_16x16x32_bf16(aH[i], wH[i][g], acc[g], 0, 0, 0);
                    acc[g] = __builtin_amdgcn_mfma_f32_16x16x32_bf16(aH[i], wL[i][g], acc[g], 0, 0, 0);
                    acc[g] = __builtin_amdgcn_mfma_f32_16x16x32_bf16(aL[i], wH[i][g], acc[g], 0, 0, 0);
                }
            }
        }

        #pragma unroll
        for (int g = 0; g < 5; ++g)
            *(f32x4*)&red[wv][g][lane][0] = acc[g];
        __syncthreads();

        if (tid < 256) {
            float gv[5];
            #pragma unroll
            for (int g = 0; g < 5; ++g)
                gv[g] = ((red[0][g][ltid][itid] + red[1][g][ltid][itid])
                      +  (red[2][g][ltid][itid] + red[3][g][ltid][itid]))
                      + ((red[4][g][ltid][itid] + red[5][g][ltid][itid])
                      +  (red[6][g][ltid][itid] + red[7][g][ltid][itid]))
                      + bias[g];

            float f  = 1.f / (1.f + expf(-gv[0]));
            float i_ = 1.f / (1.f + expf(-gv[1]));
            float ch = tanhf(gv[2]);
            float o  = 1.f / (1.f + expf(-gv[3]));
            float e_ = 1.f / (1.f + expf(-gv[4]));

            c_reg = f * c_reg + i_ * ch;
            float hl = o * tanhf(c_reg);
            float hn = e_ * expf(hl) + (1.f - e_) * hl;

            u16 hi, lo; bf16_split(hn, hi, lo);
            if (ISL1) {
                const int par = w & 1;
                __hip_atomic_store(h1f + (size_t)((par * 2 + 0) * 32768) + wof, hi,
                                   __ATOMIC_RELAXED, __HIP_MEMORY_SCOPE_AGENT);
                __hip_atomic_store(h1f + (size_t)((par * 2 + 1) * 32768) + wof, lo,
                                   __ATOMIC_RELAXED, __HIP_MEMORY_SCOPE_AGENT);
                pend = hn;
            } else {
                const int par = w & 3;
                __hip_atomic_store(h0f + (size_t)((par * 2 + 0) * 32768) + wof, hi,
                                   __ATOMIC_RELAXED, __HIP_MEMORY_SCOPE_AGENT);
                __hip_atomic_store(h0f + (size_t)((par * 2 + 1) * 32768) + wof, lo,
                                   __ATOMIC_RELAXED, __HIP_MEMORY_SCOPE_AGENT);
            }
        }
        __syncthreads();                  // drain h stores (vmcnt) before arrival
        if (tid == 0) dom_arrive(bar, domSelf, w);
    }
    // flush final deferred lstm_out value (work item SS-1)
    if (ISL1 && threadIdx.x < 256)
        lstm_out[((size_t)row * SS + (SS - 1)) * HH + jg] = pend;
}

// ---------------- persistent MFMA kernel ----------------
// 256 blocks x 512 threads = {L0: 0..127, L1: 128..255} x {J 0..31} x {m 0..3}
__global__ __launch_bounds__(512, 1) void persist_mfma(
    const u16* __restrict__ xf,
    const u16* __restrict__ wf0, const u16* __restrict__ wf1,
    const float* __restrict__ b0v, const float* __restrict__ b1v,
    u16* __restrict__ h0f, u16* __restrict__ h1f,
    float* __restrict__ lstm_out, unsigned* __restrict__ bar)
{
    __shared__ float red[8][5][64][4];          // 40 KB
    if (blockIdx.x >= 128)
        run_layer<true >(xf, wf1, h0f, h1f, b1v, lstm_out, bar, red);
    else
        run_layer<false>(xf, wf0, h0f, h1f, b0v, lstm_out, bar, red);
}

// ================= fallback path (R9, proven) =================
__global__ __launch_bounds__(256) void repack_kernel(
    const float* __restrict__ W, float* __restrict__ P, int K)
{
    __shared__ float tile[64][65];
    const int tid = threadIdx.x;
    const int kt = blockIdx.x;
    const int c0 = blockIdx.y * 64;

    for (int e = tid; e < 64 * 16; e += 256) {
        int kr = e >> 4, cq = (e & 15) * 4;
        float4 v = *(const float4*)(W + (size_t)(kt * 64 + kr) * G5 + c0 + cq);
        tile[kr][cq + 0] = v.x; tile[kr][cq + 1] = v.y;
        tile[kr][cq + 2] = v.z; tile[kr][cq + 3] = v.w;
    }
    __syncthreads();

    const int gate = c0 >> 9;
    const int jb   = c0 & 511;
    for (int e = tid; e < 64 * 16; e += 256) {
        int lr = e >> 4;
        int kq = (e & 15) * 4;
        int j  = jb + lr;
        int g  = j >> 1;
        int c  = j & 1;
        int orow = g * 10 + gate * 2 + c;
        float4 v;
        v.x = tile[kq + 0][lr]; v.y = tile[kq + 1][lr];
        v.z = tile[kq + 2][lr]; v.w = tile[kq + 3][lr];
        *(float4*)(P + (size_t)orow * K + kt * 64 + kq) = v;
    }
}

__global__ __launch_bounds__(256) void xpose_kernel(
    const float* __restrict__ x, float* __restrict__ xT)
{
    __shared__ float tile[64][68];
    const int tid = threadIdx.x;
    const int t = blockIdx.x;

    for (int e = tid; e < 64 * 16; e += 256) {
        int row = e >> 4, kq = (e & 15) * 4;
        float4 v = *(const float4*)(x + ((size_t)row * SS + t) * INF + kq);
        tile[row][kq + 0] = v.x; tile[row][kq + 1] = v.y;
        tile[row][kq + 2] = v.z; tile[row][kq + 3] = v.w;
    }
    __syncthreads();
    float* dst = xT + (size_t)t * (INF * BB);
    for (int e = tid; e < INF * BB; e += 256) {
        int k = e >> 6, r = e & 63;
        dst[(k >> 2) * 256 + r * 4 + (k & 3)] = tile[r][k];
    }
}

__device__ __forceinline__ void gemm_seg(
    const float4* __restrict__ ap, const float4* __restrict__ wq,
    int K4, int nq, float* __restrict__ acc)
{
    #pragma unroll 2
    for (int q = 0; q < nq; ++q) {
        float4 a  = ap[q * 64];
        float4 w0 = wq[q + 0 * K4];
        float4 w1 = wq[q + 1 * K4];
        float4 w2 = wq[q + 2 * K4];
        float4 w3 = wq[q + 3 * K4];
        float4 w4 = wq[q + 4 * K4];
        float4 w5 = wq[q + 5 * K4];
        float4 w6 = wq[q + 6 * K4];
        float4 w7 = wq[q + 7 * K4];
        float4 w8 = wq[q + 8 * K4];
        float4 w9 = wq[q + 9 * K4];
        acc[0]=fmaf(a.x,w0.x,acc[0]); acc[0]=fmaf(a.y,w0.y,acc[0]);
        acc[0]=fmaf(a.z,w0.z,acc[0]); acc[0]=fmaf(a.w,w0.w,acc[0]);
        acc[1]=fmaf(a.x,w1.x,acc[1]); acc[1]=fmaf(a.y,w1.y,acc[1]);
        acc[1]=fmaf(a.z,w1.z,acc[1]); acc[1]=fmaf(a.w,w1.w,acc[1]);
        acc[2]=fmaf(a.x,w2.x,acc[2]); acc[2]=fmaf(a.y,w2.y,acc[2]);
        acc[2]=fmaf(a.z,w2.z,acc[2]); acc[2]=fmaf(a.w,w2.w,acc[2]);
        acc[3]=fmaf(a.x,w3.x,acc[3]); acc[3]=fmaf(a.y,w3.y,acc[3]);
        acc[3]=fmaf(a.z,w3.z,acc[3]); acc[3]=fmaf(a.w,w3.w,acc[3]);
        acc[4]=fmaf(a.x,w4.x,acc[4]); acc[4]=fmaf(a.y,w4.y,acc[4]);
        acc[4]=fmaf(a.z,w4.z,acc[4]); acc[4]=fmaf(a.w,w4.w,acc[4]);
        acc[5]=fmaf(a.x,w5.x,acc[5]); acc[5]=fmaf(a.y,w5.y,acc[5]);
        acc[5]=fmaf(a.z,w5.z,acc[5]); acc[5]=fmaf(a.w,w5.w,acc[5]);
        acc[6]=fmaf(a.x,w6.x,acc[6]); acc[6]=fmaf(a.y,w6.y,acc[6]);
        acc[6]=fmaf(a.z,w6.z,acc[6]); acc[6]=fmaf(a.w,w6.w,acc[6]);
        acc[7]=fmaf(a.x,w7.x,acc[7]); acc[7]=fmaf(a.y,w7.y,acc[7]);
        acc[7]=fmaf(a.z,w7.z,acc[7]); acc[7]=fmaf(a.w,w7.w,acc[7]);
        acc[8]=fmaf(a.x,w8.x,acc[8]); acc[8]=fmaf(a.y,w8.y,acc[8]);
        acc[8]=fmaf(a.z,w8.z,acc[8]); acc[8]=fmaf(a.w,w8.w,acc[8]);
        acc[9]=fmaf(a.x,w9.x,acc[9]); acc[9]=fmaf(a.y,w9.y,acc[9]);
        acc[9]=fmaf(a.z,w9.z,acc[9]); acc[9]=fmaf(a.w,w9.w,acc[9]);
    }
}

__global__ __launch_bounds__(256, 2) void step512_kernel(
    const float* __restrict__ xT,
    const float* __restrict__ P0, const float* __restrict__ b0v,
    const float* __restrict__ P1, const float* __restrict__ b1v,
    float* __restrict__ h0buf, float* __restrict__ h1buf,
    float* __restrict__ c0buf, float* __restrict__ c1buf,
    float* __restrict__ lstm_out, int t)
{
    __shared__ float W_s[10 * 1024];
    __shared__ float red[4][10][64];

    const int tid  = threadIdx.x;
    const int lane = tid & 63;
    const int wv   = tid >> 6;
    const bool isL1 = (blockIdx.x >= 256);
    const int blk  = (int)blockIdx.x & 255;
    const int g    = (blk & 7) * 32 + (blk >> 3);
    const int j    = g * 2 + (wv & 1);

    const bool active = isL1 ? (t >= 1) : (t < SS);
    if (!active) return;

    const int K  = isL1 ? 1024 : 576;
    const int K4 = K >> 2;
    const int QK = K >> 2;
    const int k0 = wv * QK;

    {
        const float* Pg = (isL1 ? P1 : P0) + (size_t)g * 10 * K;
        const int n4 = 10 * K / 4;
        for (int i = tid; i < n4; i += 256)
            *(float4*)&W_s[i * 4] = *(const float4*)(Pg + (size_t)i * 4);
    }
    __syncthreads();

    const int tm1 = t - 1;
    const float* h0prev = h0buf + ((t + 1) & 1) * (BB * HH);
    const float* h0cur  = h0buf + (tm1 & 1) * (BB * HH);
    const float* h1prev = h1buf + ((tm1 + 1) & 1) * (BB * HH);

    const float4* wq0 = (const float4*)W_s + (k0 >> 2);

    float acc[10];
    #pragma unroll
    for (int r = 0; r < 10; ++r) acc[r] = 0.f;

    if (!isL1) {
        if (wv == 0) {
            const float4* aX = (const float4*)(xT + (size_t)t * (INF * BB)) + lane;
            const float4* aH = (const float4*)h0prev + lane;
            gemm_seg(aX, wq0,      K4, 16, acc);
            gemm_seg(aH, wq0 + 16, K4, 20, acc);
        } else {
            const float4* aH = (const float4*)h0prev + (36 * wv - 16) * 64 + lane;
            gemm_seg(aH, wq0, K4, 36, acc);
        }
    } else {
        const float* src = (wv < 2) ? h0cur : h1prev;
        const float4* aH = (const float4*)src + (wv & 2 ? (wv - 2) : wv) * 4096 + lane;
        gemm_seg(aH, wq0, K4, 64, acc);
    }

    #pragma unroll
    for (int r = 0; r < 10; ++r) red[wv][r][lane] = acc[r];
    __syncthreads();

    if (wv < 2) {
        const float* bv = isL1 ? b1v : b0v;
        float gv[5];
        #pragma unroll
        for (int gate = 0; gate < 5; ++gate) {
            int r = gate * 2 + wv;
            gv[gate] = red[0][r][lane] + red[1][r][lane]
                     + red[2][r][lane] + red[3][r][lane] + bv[gate * HH + j];
        }
        float f  = 1.f / (1.f + expf(-gv[0]));
        float i_ = 1.f / (1.f + expf(-gv[1]));
        float ch = tanhf(gv[2]);
        float o  = 1.f / (1.f + expf(-gv[3]));
        float e_ = 1.f / (1.f + expf(-gv[4]));

        float* cb = (isL1 ? c1buf : c0buf) + j * BB + lane;
        float c = f * (*cb) + i_ * ch;
        *cb = c;
        float hl = o * tanhf(c);
        float hn = e_ * expf(hl) + (1.f - e_) * hl;

        const int hoff = (j >> 2) * 256 + lane * 4 + (j & 3);
        if (!isL1) {
            h0buf[(t & 1) * (BB * HH) + hoff] = hn;
        } else {
            h1buf[(tm1 & 1) * (BB * HH) + hoff] = hn;
            lstm_out[((size_t)lane * SS + tm1) * HH + j] = hn;
        }
    }
}

// ---------------- attention epilogue ----------------
__global__ __launch_bounds__(256) void attn_kernel(
    const float* __restrict__ lstm_out,
    const float* __restrict__ Wa, const float* __restrict__ ba,
    const float* __restrict__ Wfc, const float* __restrict__ bfc,
    float* __restrict__ dout)
{
    const int b = blockIdx.x;
    const int tid = threadIdx.x;
    const int lane = tid & 63;
    const int wave = tid >> 6;

    __shared__ float wa_s[HH];
    __shared__ float logit[SS];
    __shared__ float wred[4];

    for (int ii = tid; ii < HH; ii += 256) wa_s[ii] = Wa[ii];
    __syncthreads();

    const float* Lb = lstm_out + (size_t)b * SS * HH;

    for (int tt = wave; tt < SS; tt += 4) {
        const float* rowp = Lb + (size_t)tt * HH;
        float s = 0.f;
        for (int jc = lane; jc < HH; jc += 64) s += rowp[jc] * wa_s[jc];
        #pragma unroll
        for (int off = 32; off > 0; off >>= 1) s += __shfl_down(s, off, 64);
        if (lane == 0) logit[tt] = s + ba[0];
    }
    __syncthreads();

    float m = -1e30f;
    for (int ii = tid; ii < SS; ii += 256) m = fmaxf(m, logit[ii]);
    #pragma unroll
    for (int off = 32; off > 0; off >>= 1) m = fmaxf(m, __shfl_down(m, off, 64));
    if (lane == 0) wred[wave] = m;
    __syncthreads();
    m = fmaxf(fmaxf(wred[0], wred[1]), fmaxf(wred[2], wred[3]));
    __syncthreads();

    float ssum = 0.f;
    for (int ii = tid; ii < SS; ii += 256) {
        float e = expf(logit[ii] - m);
        logit[ii] = e;
        ssum += e;
    }
    #pragma unroll
    for (int off = 32; off > 0; off >>= 1) ssum += __shfl_down(ssum, off, 64);
    if (lane == 0) wred[wave] = ssum;
    __syncthreads();
    ssum = wred[0] + wred[1] + wred[2] + wred[3];
    float inv = 1.f / ssum;
    __syncthreads();

    for (int ii = tid; ii < SS; ii += 256) {
        float a = logit[ii] * inv;
        logit[ii] = a;
        dout[BB + (size_t)b * SS + ii] = a;
    }
    __syncthreads();

    float ctx0 = 0.f, ctx1 = 0.f;
    for (int tt = 0; tt < SS; ++tt) {
        float a = logit[tt];
        ctx0 += a * Lb[(size_t)tt * HH + tid];
        ctx1 += a * Lb[(size_t)tt * HH + tid + 256];
    }

    float p = ctx0 * Wfc[tid] + ctx1 * Wfc[tid + 256];
    #pragma unroll
    for (int off = 32; off > 0; off >>= 1) p += __shfl_down(p, off, 64);
    __syncthreads();
    if (lane == 0) wred[wave] = p;
    __syncthreads();
    if (tid == 0) dout[b] = wred[0] + wred[1] + wred[2] + wred[3] + bfc[0];
}

extern "C" void kernel_launch(void* const* d_in, const int* in_sizes, int n_in,
                              void* d_out, int out_size, void* d_ws, size_t ws_size,
                              hipStream_t stream) {
    const float* x   = (const float*)d_in[0];
    const float* W0  = (const float*)d_in[1];
    const float* b0  = (const float*)d_in[2];
    const float* W1  = (const float*)d_in[3];
    const float* b1  = (const float*)d_in[4];
    const float* Wa  = (const float*)d_in[5];
    const float* ba  = (const float*)d_in[6];
    const float* Wfc = (const float*)d_in[7];
    const float* bfc = (const float*)d_in[8];
    float* out = (float*)d_out;
    float* ws  = (float*)d_ws;

    float* h0q  = ws;                              // 2*B*H (fallback)
    float* h1q  = h0q + 2 * BB * HH;               // 2*B*H (fallback)
    float* c0   = h1q + 2 * BB * HH;               // B*H (fallback)
    float* c1   = c0 + BB * HH;                    // B*H (fallback)
    u16*   h0f  = (u16*)(c1 + BB * HH);            // 262144 u16 (4 par x 2 term)
    u16*   h1f  = h0f + 262144;                    // 131072 u16 (2 par x 2 term)
    unsigned* bar = (unsigned*)(h1f + 131072);     // 1024 u32 (8 doms x 32)
    float* lstm = (float*)(bar + 1024);            // B*S*H
    float* WA   = lstm + (size_t)BB * SS * HH;     // P0 (fb) == wf0 (frag)
    float* WB   = WA + (size_t)G5 * (INF + HH);    // P1 (fb) == wf1 (frag)
    float* XF   = WB + (size_t)G5 * (HH + HH);     // xT (fb) == xf (frag)
    u16* wf0 = (u16*)WA;
    u16* wf1 = (u16*)WB;
    u16* xf  = (u16*)XF;

    // zero: fallback state (196608 f) + h0f (131072 f) + h1f (65536 f) + bar (1024 f)
    const int n_init = 6 * BB * HH + 262144 / 2 + 131072 / 2 + 1024;
    init_kernel<<<(n_init + 255) / 256, 256, 0, stream>>>(ws, n_init);

    wrepack_frag<<<dim3(18, 32), 256, 0, stream>>>(W0, wf0, 18);
    wrepack_frag<<<dim3(32, 32), 256, 0, stream>>>(W1, wf1, 32);
    xfrag_kernel<<<SS, 256, 0, stream>>>(x, xf);

    void* args[] = { (void*)&xf, (void*)&wf0, (void*)&wf1, (void*)&b0, (void*)&b1,
                     (void*)&h0f, (void*)&h1f, (void*)&lstm, (void*)&bar };
    hipError_t cerr = hipLaunchCooperativeKernel((void*)persist_mfma,
                                                 dim3(256), dim3(512),
                                                 args, 0, stream);
    if (cerr != hipSuccess) {
        repack_kernel<<<dim3((INF + HH) / 64, 40), 256, 0, stream>>>(W0, WA, INF + HH);
        repack_kernel<<<dim3((HH + HH) / 64, 40), 256, 0, stream>>>(W1, WB, HH + HH);
        xpose_kernel<<<SS, 256, 0, stream>>>(x, XF);
        for (int t = 0; t <= SS; ++t) {
            step512_kernel<<<512, 256, 0, stream>>>(XF, WA, b0, WB, b1,
                                                    h0q, h1q, c0, c1, lstm, t);
        }
    }

    attn_kernel<<<BB, 256, 0, stream>>>(lstm, Wa, ba, Wfc, bfc, out);
}